// Round 2
// baseline (513.167 us; speedup 1.0000x reference)
//
#include <hip/hip_runtime.h>
#include <math.h>

#define BLOCK 256
#define N_MOD 8
#define NEG_INF (-__builtin_inff())

// Branchless top-2 over a masked row, carrying the softmax weight of each
// winner so no indexed gather is needed. Strict '>' preserves lax.top_k's
// lower-index-first tie-breaking.
__device__ __forceinline__ float row_result(float4 x0, float4 x1, int4 m0, int4 m1,
                                            const float sw[N_MOD]) {
    float v[N_MOD];
    v[0] = m0.x ? x0.x : NEG_INF;
    v[1] = m0.y ? x0.y : NEG_INF;
    v[2] = m0.z ? x0.z : NEG_INF;
    v[3] = m0.w ? x0.w : NEG_INF;
    v[4] = m1.x ? x1.x : NEG_INF;
    v[5] = m1.y ? x1.y : NEG_INF;
    v[6] = m1.z ? x1.z : NEG_INF;
    v[7] = m1.w ? x1.w : NEG_INF;

    float b1 = NEG_INF, b2 = NEG_INF, w1 = 0.0f, w2 = 0.0f;
    #pragma unroll
    for (int j = 0; j < N_MOD; ++j) {
        float vj = v[j], wj = sw[j];
        bool gt1 = vj > b1;
        bool gt2 = vj > b2;
        float nb2 = gt1 ? b1 : (gt2 ? vj : b2);
        float nw2 = gt1 ? w1 : (gt2 ? wj : w2);
        b1 = gt1 ? vj : b1;
        w1 = gt1 ? wj : w1;
        b2 = nb2;
        w2 = nw2;
    }
    // scattered @ softW + mean(top2)
    return b1 * w1 + b2 * w2 + 0.5f * (b1 + b2);
}

__global__ __launch_bounds__(BLOCK) void wta_kernel(
    const float* __restrict__ x,
    const int*   __restrict__ mask,
    const float* __restrict__ W,
    float*       __restrict__ out,
    int B)
{
    const int rows_per_block = BLOCK * 2;
    int ra = blockIdx.x * rows_per_block + threadIdx.x;  // row A
    int rb = ra + BLOCK;                                 // row B

    // --- issue all 8 streaming loads up front (max memory-level parallelism) ---
    float4 xa0, xa1, xb0, xb1;
    int4   ma0, ma1, mb0, mb1;
    bool va = ra < B, vb = rb < B;
    if (va) {
        const float4* p = (const float4*)(x + (size_t)ra * N_MOD);
        xa0 = p[0]; xa1 = p[1];
        const int4* q = (const int4*)(mask + (size_t)ra * N_MOD);
        ma0 = q[0]; ma1 = q[1];
    }
    if (vb) {
        const float4* p = (const float4*)(x + (size_t)rb * N_MOD);
        xb0 = p[0]; xb1 = p[1];
        const int4* q = (const int4*)(mask + (size_t)rb * N_MOD);
        mb0 = q[0]; mb1 = q[1];
    }

    // --- softmax(W) per-thread: wave-uniform (compiler scalarizes the loads),
    //     pure VALU, overlaps with the in-flight streaming loads. No LDS/barrier.
    float sw[N_MOD];
    #pragma unroll
    for (int j = 0; j < N_MOD; ++j) sw[j] = W[j];
    float m = sw[0];
    #pragma unroll
    for (int j = 1; j < N_MOD; ++j) m = fmaxf(m, sw[j]);
    float s = 0.0f;
    #pragma unroll
    for (int j = 0; j < N_MOD; ++j) { sw[j] = __expf(sw[j] - m); s += sw[j]; }
    float inv = 1.0f / s;
    #pragma unroll
    for (int j = 0; j < N_MOD; ++j) sw[j] *= inv;

    if (va) out[ra] = row_result(xa0, xa1, ma0, ma1, sw);
    if (vb) out[rb] = row_result(xb0, xb1, mb0, mb1, sw);
}

extern "C" void kernel_launch(void* const* d_in, const int* in_sizes, int n_in,
                              void* d_out, int out_size, void* d_ws, size_t ws_size,
                              hipStream_t stream) {
    const float* x    = (const float*)d_in[0];
    const int*   mask = (const int*)d_in[1];
    const float* W    = (const float*)d_in[2];
    float*       out  = (float*)d_out;

    int B = out_size;  // 8388608 rows, one output per row
    int rows_per_block = BLOCK * 2;
    int grid = (B + rows_per_block - 1) / rows_per_block;
    wta_kernel<<<grid, BLOCK, 0, stream>>>(x, mask, W, out, B);
}